// Round 9
// baseline (448.223 us; speedup 1.0000x reference)
//
#include <hip/hip_runtime.h>

// ConvGeodesic: B=50000, R=5, A=8, K=2, O=32, I=32
// conv[b,n] = sum_k p[b,k] * W[k,n]   (M=50000, K=1280, N=256)
//   p[b,(ra,i)] = sum_t bary[b,ra,t]*signal[b,ra,t,i]
//   W[(ra,i),(c,o)] = sum_kk kernel[r,(c+a)%8,kk,o,i]
// GEMM on bf16 MFMA, 3-term hi/lo split (hi*hi + hi*lo + lo*hi).
// R9: TWO-DEEP signal/bary register prefetch (sets SA/SB) — sig(k) issued at
// body(k-2), consumed at body(k): ~2 iters of latency cover, so waves never
// stall on HBM. W loads split by plane (bh block, then bl block) to keep peak
// register pressure under the (256,3) unified cap (R7: overflow => 487MB spill).
// Light lgkm-only barrier keeps the deep prefetch in flight across iterations.
// out[b,:] = relu(conv)[b, argmax_c ||relu(conv)[b,c,:]||, :]

#define B_TOT 50000
#define NRA 40

typedef __attribute__((ext_vector_type(8))) short short8v;   // 8 bf16 (4 VGPRs)
typedef __attribute__((ext_vector_type(4))) float f32x4;

// W planes, n-major k-minor per ra-slab: [ra][n=256][k'=32] bf16 (1.31 MB each)
__device__ __align__(16) unsigned short W_hi_g[NRA * 256 * 32];
__device__ __align__(16) unsigned short W_lo_g[NRA * 256 * 32];

static __device__ __forceinline__ unsigned short f2bf(float x) {   // rne
    unsigned u = __float_as_uint(x);
    u += 0x7FFFu + ((u >> 16) & 1u);
    return (unsigned short)(u >> 16);
}
static __device__ __forceinline__ float bf2f(unsigned short h) {
    return __uint_as_float(((unsigned)h) << 16);
}

// LDS-write visibility barrier WITHOUT the vmcnt(0) drain __syncthreads would
// emit — essential: the 2-deep sig prefetch must survive the barrier.
static __device__ __forceinline__ void lds_barrier() {
    asm volatile("s_waitcnt lgkmcnt(0)" ::: "memory");
    __builtin_amdgcn_s_barrier();
    asm volatile("" ::: "memory");
}

__global__ __launch_bounds__(256) void build_w_kernel(const float* __restrict__ kern) {
    int e = blockIdx.x * 256 + threadIdx.x;   // e = ((ra*256)+n)*32 + i
    int i = e & 31;
    int n = (e >> 5) & 255;
    int ra = e >> 13;
    int r = ra >> 3, a = ra & 7;
    int c = n >> 5, o = n & 31;
    int a2 = (c + a) & 7;
    // kernel (R,A,K,O,I); kk stride = 1024
    const float* p = kern + ((((r * 8 + a2) * 2) * 32 + o) * 32 + i);
    float w = p[0] + p[1024];
    unsigned short hi = f2bf(w);
    unsigned short lo = f2bf(w - bf2f(hi));
    W_hi_g[e] = hi;
    W_lo_g[e] = lo;
}

static __device__ __forceinline__ void pcomp(float by0, float by1, float by2,
                                             const float4& a, const float4& b,
                                             const float4& c, float* d) {
    d[0] = fmaf(by2, c.x, fmaf(by1, b.x, by0 * a.x));
    d[1] = fmaf(by2, c.y, fmaf(by1, b.y, by0 * a.y));
    d[2] = fmaf(by2, c.z, fmaf(by1, b.z, by0 * a.z));
    d[3] = fmaf(by2, c.w, fmaf(by1, b.w, by0 * a.w));
}

static __device__ __forceinline__ void pack_write(unsigned short* buf, int idx, const float* v) {
    unsigned short h[4], l[4];
#pragma unroll
    for (int k = 0; k < 4; ++k) {
        h[k] = f2bf(v[k]);
        l[k] = f2bf(v[k] - bf2f(h[k]));
    }
    uint2 H, L;
    H.x = (unsigned)h[0] | ((unsigned)h[1] << 16);
    H.y = (unsigned)h[2] | ((unsigned)h[3] << 16);
    L.x = (unsigned)l[0] | ((unsigned)l[1] << 16);
    L.y = (unsigned)l[2] | ((unsigned)l[3] << 16);
    *(uint2*)(buf + idx) = H;            // hi plane
    *(uint2*)(buf + 2560 + idx) = L;     // lo plane (+64*40 ushorts)
}

struct SigSet {                      // one prefetch stage: 24 + 3 VGPRs
    float4 s0, s1, s2, s3, s4, s5;
    float by0, by1, by2;
};

__global__ __launch_bounds__(256, 3) void conv_geo_kernel(const float* __restrict__ sig,
                                                          const float* __restrict__ bary,
                                                          float* __restrict__ out) {
    // LDS union: two p buffers (hi+lo [64][40] bf16 = 10240 B each, 20480 B total);
    // epilogue act half-tile [32][264] f32 = 33792 B.  -> 3 blocks/CU (VGPR-limited).
    __shared__ __align__(16) float smem[8448];
    unsigned short* pb0 = (unsigned short*)smem;          // buffer 0
    unsigned short* pb1 = pb0 + 5120;                     // buffer 1

    const int tid  = threadIdx.x;
    const int lane = tid & 63;
    const int wave = tid >> 6;       // 4 waves, wave w owns cols [64w, 64w+64)
    const int b_l  = tid >> 2;       // 0..63: staging row
    const int q    = tid & 3;
    const int b0   = blockIdx.x * 64;
    int bld = b0 + b_l; if (bld > B_TOT - 1) bld = B_TOT - 1;   // clamp loads; stores guarded
    const size_t sig_row = (size_t)bld * 40;

    f32x4 acc[4][4];                 // [mi][ni]
#pragma unroll
    for (int mi = 0; mi < 4; ++mi)
#pragma unroll
        for (int ni = 0; ni < 4; ++ni) acc[mi][ni] = (f32x4){0.f, 0.f, 0.f, 0.f};

    const int wcol = (wave * 64 + (lane & 15)) * 32 + (lane >> 4) * 8;  // B-frag ushort idx in slab
    const int poff = (lane & 15) * 40 + (lane >> 4) * 8;                // A-frag base (16B-aligned)
    const int widx = b_l * 40 + q * 4;                                  // p write base

    SigSet SA, SB;
    auto load_set = [&](SigSet& S, int ra) {
        const float* sp = sig + (sig_row + ra) * 96 + q * 4;
        S.s0 = *(const float4*)(sp);      S.s1 = *(const float4*)(sp + 16);
        S.s2 = *(const float4*)(sp + 32); S.s3 = *(const float4*)(sp + 48);
        S.s4 = *(const float4*)(sp + 64); S.s5 = *(const float4*)(sp + 80);
        const float* bp = bary + (sig_row + ra) * 3;
        S.by0 = bp[0]; S.by1 = bp[1]; S.by2 = bp[2];
    };
    auto store_p = [&](unsigned short* wrbuf, SigSet& S) {
        float pa[4], pbv[4];
        pcomp(S.by0, S.by1, S.by2, S.s0, S.s2, S.s4, pa);    // i = 4q..4q+3
        pcomp(S.by0, S.by1, S.by2, S.s1, S.s3, S.s5, pbv);   // i = 4q+16..4q+19
        pack_write(wrbuf, widx, pa);
        pack_write(wrbuf, widx + 16, pbv);
    };

    // prologue: p(0)->pb0; SB holds sig(1); SA refilled with sig(2) (in flight)
    load_set(SA, 0);
    load_set(SB, 1);
    store_p(pb0, SA);
    load_set(SA, 2);
    lds_barrier();

    // body invariant: rdbuf = p(ra); `ready` = sig(ra+1) (issued at body(ra-2),
    // ~2 iters of cover); the other set has sig(ra+2) in flight.
    auto body = [&](int ra, unsigned short* rdbuf, unsigned short* wrbuf, SigSet& ready) {
        if (ra + 1 < NRA) store_p(wrbuf, ready);     // only vmcnt wait, ~retired already
        if (ra + 3 < NRA) load_set(ready, ra + 3);   // refill same set, 2 iters ahead
        const unsigned short* whp = W_hi_g + ra * 8192 + wcol;
        const unsigned short* wlp = W_lo_g + ra * 8192 + wcol;
        // ---- hi-plane W + 32 MFMAs (ah*bh, al*bh) ----
        short8v w0 = *(const short8v*)(whp);
        short8v w1 = *(const short8v*)(whp + 512);
        short8v w2 = *(const short8v*)(whp + 1024);
        short8v w3 = *(const short8v*)(whp + 1536);
#pragma unroll
        for (int mi = 0; mi < 4; ++mi) {
            const unsigned short* pr = rdbuf + mi * 640 + poff;   // 16 rows * 40
            short8v ah = *(const short8v*)pr;
            short8v al = *(const short8v*)(pr + 2560);
            acc[mi][0] = __builtin_amdgcn_mfma_f32_16x16x32_bf16(ah, w0, acc[mi][0], 0, 0, 0);
            acc[mi][1] = __builtin_amdgcn_mfma_f32_16x16x32_bf16(ah, w1, acc[mi][1], 0, 0, 0);
            acc[mi][2] = __builtin_amdgcn_mfma_f32_16x16x32_bf16(ah, w2, acc[mi][2], 0, 0, 0);
            acc[mi][3] = __builtin_amdgcn_mfma_f32_16x16x32_bf16(ah, w3, acc[mi][3], 0, 0, 0);
            acc[mi][0] = __builtin_amdgcn_mfma_f32_16x16x32_bf16(al, w0, acc[mi][0], 0, 0, 0);
            acc[mi][1] = __builtin_amdgcn_mfma_f32_16x16x32_bf16(al, w1, acc[mi][1], 0, 0, 0);
            acc[mi][2] = __builtin_amdgcn_mfma_f32_16x16x32_bf16(al, w2, acc[mi][2], 0, 0, 0);
            acc[mi][3] = __builtin_amdgcn_mfma_f32_16x16x32_bf16(al, w3, acc[mi][3], 0, 0, 0);
        }
        // ---- lo-plane W (reuse regs) + 16 MFMAs (ah*bl) ----
        w0 = *(const short8v*)(wlp);
        w1 = *(const short8v*)(wlp + 512);
        w2 = *(const short8v*)(wlp + 1024);
        w3 = *(const short8v*)(wlp + 1536);
#pragma unroll
        for (int mi = 0; mi < 4; ++mi) {
            short8v ah = *(const short8v*)(rdbuf + mi * 640 + poff);
            acc[mi][0] = __builtin_amdgcn_mfma_f32_16x16x32_bf16(ah, w0, acc[mi][0], 0, 0, 0);
            acc[mi][1] = __builtin_amdgcn_mfma_f32_16x16x32_bf16(ah, w1, acc[mi][1], 0, 0, 0);
            acc[mi][2] = __builtin_amdgcn_mfma_f32_16x16x32_bf16(ah, w2, acc[mi][2], 0, 0, 0);
            acc[mi][3] = __builtin_amdgcn_mfma_f32_16x16x32_bf16(ah, w3, acc[mi][3], 0, 0, 0);
        }
        lds_barrier();   // lgkm-only; sig prefetch stays in flight
    };

    for (int ra = 0; ra < NRA; ra += 2) {
        body(ra,     pb0, pb1, SB);
        body(ra + 1, pb1, pb0, SA);
    }

    // ---- epilogue: relu + norms + argmax + select, two 32-row passes through LDS ----
    // D layout: row = 16*mi + 4*(lane>>4) + j, col = 64*wave + 16*ni + (lane&15)   [m89-verified]
    const int colb = wave * 64 + (lane & 15);
    const int rsub = (lane >> 4) * 4;
#pragma unroll
    for (int ph = 0; ph < 2; ++ph) {
        __syncthreads();
#pragma unroll
        for (int mh = 0; mh < 2; ++mh) {
            int mi = ph * 2 + mh;
#pragma unroll
            for (int ni = 0; ni < 4; ++ni)
#pragma unroll
                for (int j = 0; j < 4; ++j)
                    smem[(mh * 16 + rsub + j) * 264 + colb + ni * 16] =
                        fmaxf(acc[mi][ni][j], 0.0f);
        }
        __syncthreads();
        int bb = tid >> 3;          // 0..31
        int c  = tid & 7;
        float n2 = 0.0f;
#pragma unroll
        for (int t = 0; t < 8; ++t) {
            float4 v = *(const float4*)&smem[bb * 264 + c * 32 + t * 4];
            n2 = fmaf(v.x, v.x, n2); n2 = fmaf(v.y, v.y, n2);
            n2 = fmaf(v.z, v.z, n2); n2 = fmaf(v.w, v.w, n2);
        }
        int bc = c;
#pragma unroll
        for (int m = 1; m < 8; m <<= 1) {   // argmax, tie -> lowest c (numpy first-max)
            float on2 = __shfl_xor(n2, m, 64);
            int obc = __shfl_xor(bc, m, 64);
            if (on2 > n2 || (on2 == n2 && obc < bc)) { n2 = on2; bc = obc; }
        }
        int b = b0 + ph * 32 + bb;
        if (b < B_TOT) {
            float4 v = *(const float4*)&smem[bb * 264 + bc * 32 + (tid & 7) * 4];
            *(float4*)&out[(size_t)b * 32 + (tid & 7) * 4] = v;
        }
    }
}

extern "C" void kernel_launch(void* const* d_in, const int* in_sizes, int n_in,
                              void* d_out, int out_size, void* d_ws, size_t ws_size,
                              hipStream_t stream) {
    const float* sig  = (const float*)d_in[0];   // (B,R,A,3,I)
    const float* bary = (const float*)d_in[1];   // (B,R,A,3)
    const float* kern = (const float*)d_in[2];   // (R,A,K,O,I)
    float* out = (float*)d_out;                  // (B,O)

    build_w_kernel<<<(NRA * 256 * 32) / 256, 256, 0, stream>>>(kern);
    conv_geo_kernel<<<(B_TOT + 63) / 64, 256, 0, stream>>>(sig, bary, out);
}

// Round 10
// 289.021 us; speedup vs baseline: 1.5508x; 1.5508x over previous
//
#include <hip/hip_runtime.h>

// ConvGeodesic: B=50000, R=5, A=8, K=2, O=32, I=32
// conv[b,n] = sum_k p[b,k] * W[k,n]   (M=50000, K=1280, N=256)
//   p[b,(ra,i)] = sum_t bary[b,ra,t]*signal[b,ra,t,i]
//   W[(ra,i),(c,o)] = sum_kk kernel[r,(c+a)%8,kk,o,i]
// GEMM on bf16 MFMA, 3-term hi/lo split (hi*hi + hi*lo + lo*hi).
// R10: signal+bary staged into a 2-slot LDS ring by global_load_lds DMA issued
// 2 iterations ahead (zero VGPR residency -> no spill; counted vmcnt(7) keeps
// the next slot's DMAs in flight across barriers). A-fragments (pullback +
// bf16 hi/lo) are computed per-lane directly from the LDS signal tile — the
// p-LDS round trip, pack_write and SigSets are gone. LDS sig tile is
// XOR-swizzled (inverse-swizzled DMA *source*, swizzled *read* — m173 pattern)
// to kill the 16-way bank conflict of the 384B row stride.
// out[b,:] = relu(conv)[b, argmax_c ||relu(conv)[b,c,:]||, :]

#define B_TOT 50000
#define NRA 40
#define SLOT_BYTES 25600   // 24576 sig + 1024 bary region

typedef __attribute__((ext_vector_type(8))) short short8v;   // 8 bf16 (4 VGPRs)
typedef __attribute__((ext_vector_type(4))) float f32x4;
typedef const __attribute__((address_space(1))) unsigned int* gp1_t;
typedef __attribute__((address_space(3))) unsigned int* lp3_t;

// W planes, n-major k-minor per ra-slab: [ra][n=256][k'=32] bf16 (1.31 MB each)
__device__ __align__(16) unsigned short W_hi_g[NRA * 256 * 32];
__device__ __align__(16) unsigned short W_lo_g[NRA * 256 * 32];

static __device__ __forceinline__ unsigned short f2bf(float x) {   // rne
    unsigned u = __float_as_uint(x);
    u += 0x7FFFu + ((u >> 16) & 1u);
    return (unsigned short)(u >> 16);
}
static __device__ __forceinline__ float bf2f(unsigned short h) {
    return __uint_as_float(((unsigned)h) << 16);
}

__global__ __launch_bounds__(256) void build_w_kernel(const float* __restrict__ kern) {
    int e = blockIdx.x * 256 + threadIdx.x;   // e = ((ra*256)+n)*32 + i
    int i = e & 31;
    int n = (e >> 5) & 255;
    int ra = e >> 13;
    int r = ra >> 3, a = ra & 7;
    int c = n >> 5, o = n & 31;
    int a2 = (c + a) & 7;
    // kernel (R,A,K,O,I); kk stride = 1024
    const float* p = kern + ((((r * 8 + a2) * 2) * 32 + o) * 32 + i);
    float w = p[0] + p[1024];
    unsigned short hi = f2bf(w);
    unsigned short lo = f2bf(w - bf2f(hi));
    W_hi_g[e] = hi;
    W_lo_g[e] = lo;
}

static __device__ __forceinline__ short8v pack8(const unsigned short* h) {
    union { unsigned u[4]; short8v v; } cv;
#pragma unroll
    for (int k = 0; k < 4; ++k)
        cv.u[k] = (unsigned)h[2 * k] | ((unsigned)h[2 * k + 1] << 16);
    return cv.v;
}

__global__ __launch_bounds__(256, 3) void conv_geo_kernel(const float* __restrict__ sig,
                                                          const float* __restrict__ bary,
                                                          float* __restrict__ out) {
    // LDS: 2 slots x (24576 B swizzled sig [64][384B] + 1024 B bary [3][64]f32 region)
    // = 51200 B; epilogue act [32][264] f32 = 33792 B unions into slot space.
    // 3 blocks/CU: LDS 153.6K/160K, VGPR ~149 unified.
    __shared__ __align__(16) char lds_raw[2 * SLOT_BYTES];

    const int tid  = threadIdx.x;
    const int lane = tid & 63;
    const int wave = tid >> 6;       // 4 waves, wave w owns cols [64w, 64w+64)
    const int b0   = blockIdx.x * 64;

    f32x4 acc[4][4];                 // [mi][ni]
#pragma unroll
    for (int mi = 0; mi < 4; ++mi)
#pragma unroll
        for (int ni = 0; ni < 4; ++ni) acc[mi][ni] = (f32x4){0.f, 0.f, 0.f, 0.f};

    const int wcol = (wave * 64 + (lane & 15)) * 32 + (lane >> 4) * 8;  // B-frag ushort idx in slab

    // ---- DMA source offsets (bytes), ra-invariant parts ----
    // sig issue j: LDS byte L = j*4096 + tid*16 -> (row = L/384, cb = L%384);
    // source column = cb ^ ((row&7)<<4)  (inverse swizzle == swizzle, involution)
    unsigned sigoff[6];
#pragma unroll
    for (int j = 0; j < 6; ++j) {
        int L   = j * 4096 + tid * 16;
        int row = L / 384;
        int cb  = L - row * 384;
        int col = cb ^ ((row & 7) << 4);
        int rowc = b0 + row; if (rowc > B_TOT - 1) rowc = B_TOT - 1;
        sigoff[j] = (unsigned)rowc * 40u * 384u + (unsigned)col;
    }
    // bary: logical word G = t*64 + rr (G<192); threads 192..255 duplicate G-192 into pad.
    unsigned baryoff;
    {
        int G  = (tid < 192) ? tid : tid - 192;
        int rr = G & 63;
        int t  = G >> 6;
        int rowc = b0 + rr; if (rowc > B_TOT - 1) rowc = B_TOT - 1;
        baryoff = (unsigned)rowc * 40u * 12u + (unsigned)t * 4u;
    }

    const char* sigc  = (const char*)sig;
    const char* baryc = (const char*)bary;
    auto issue_slot = [&](int ra, int slot) {
        char* lb = lds_raw + slot * SLOT_BYTES;
#pragma unroll
        for (int j = 0; j < 6; ++j) {
            const void* gp = sigc + ((size_t)sigoff[j] + (size_t)ra * 384u);
            void* lp = lb + j * 4096 + tid * 16;
            __builtin_amdgcn_global_load_lds((gp1_t)gp, (lp3_t)lp, 16, 0, 0);
        }
        const void* gpb = baryc + ((size_t)baryoff + (size_t)ra * 12u);
        void* lpb = lb + 24576 + tid * 4;
        __builtin_amdgcn_global_load_lds((gp1_t)gpb, (lp3_t)lpb, 4, 0, 0);
    };

    // prologue: fill both slots' DMAs (7 instructions each, fire-and-forget)
    issue_slot(0, 0);
    issue_slot(1, 1);

    const int rr_base = lane & 15;          // + 16*mi = row in tile
    const int i0     = (lane >> 4) * 8;     // k-offset within ra-chunk

    for (int ra = 0; ra < NRA; ++ra) {
        const int slot = ra & 1;
        // ---- wait own DMAs for this slot (leave next slot's 7 in flight) ----
        if (ra < NRA - 1) asm volatile("s_waitcnt vmcnt(7)" ::: "memory");
        else              asm volatile("s_waitcnt vmcnt(0)" ::: "memory");
        __builtin_amdgcn_s_barrier();       // all waves' DMAs for this slot landed
        asm volatile("" ::: "memory");

        const char*  slotc = lds_raw + slot * SLOT_BYTES;
        const float* bw    = (const float*)(slotc + 24576);   // [3][64]

        // ---- W frags for ra (L2-hit, contiguous 1KB per frag) ----
        short8v bh[4], bl[4];
        {
            const unsigned short* whp = W_hi_g + ra * 8192 + wcol;
            const unsigned short* wlp = W_lo_g + ra * 8192 + wcol;
#pragma unroll
            for (int ni = 0; ni < 4; ++ni) {
                bh[ni] = *(const short8v*)(whp + ni * 512);
                bl[ni] = *(const short8v*)(wlp + ni * 512);
            }
        }

        // ---- per-mi: pullback from LDS sig -> bf16 hi/lo A-frags -> MFMA ----
#pragma unroll
        for (int mi = 0; mi < 4; ++mi) {
            const int rr  = mi * 16 + rr_base;
            const int swz = (rr & 7) << 4;
            const char* rowp = slotc + rr * 384;
            float4 a0 = *(const float4*)(rowp + ((  0 + i0 * 4)      ^ swz));
            float4 a1 = *(const float4*)(rowp + ((  0 + i0 * 4 + 16) ^ swz));
            float4 b1 = *(const float4*)(rowp + ((128 + i0 * 4)      ^ swz));
            float4 b2 = *(const float4*)(rowp + ((128 + i0 * 4 + 16) ^ swz));
            float4 c1 = *(const float4*)(rowp + ((256 + i0 * 4)      ^ swz));
            float4 c2 = *(const float4*)(rowp + ((256 + i0 * 4 + 16) ^ swz));
            float by0 = bw[rr], by1 = bw[64 + rr], by2 = bw[128 + rr];
            float p[8];
            p[0] = fmaf(by2, c1.x, fmaf(by1, b1.x, by0 * a0.x));
            p[1] = fmaf(by2, c1.y, fmaf(by1, b1.y, by0 * a0.y));
            p[2] = fmaf(by2, c1.z, fmaf(by1, b1.z, by0 * a0.z));
            p[3] = fmaf(by2, c1.w, fmaf(by1, b1.w, by0 * a0.w));
            p[4] = fmaf(by2, c2.x, fmaf(by1, b2.x, by0 * a1.x));
            p[5] = fmaf(by2, c2.y, fmaf(by1, b2.y, by0 * a1.y));
            p[6] = fmaf(by2, c2.z, fmaf(by1, b2.z, by0 * a1.z));
            p[7] = fmaf(by2, c2.w, fmaf(by1, b2.w, by0 * a1.w));
            unsigned short hh[8], ll[8];
#pragma unroll
            for (int j = 0; j < 8; ++j) {
                hh[j] = f2bf(p[j]);
                ll[j] = f2bf(p[j] - bf2f(hh[j]));
            }
            short8v ah = pack8(hh), al = pack8(ll);
#pragma unroll
            for (int ni = 0; ni < 4; ++ni) {
                acc[mi][ni] = __builtin_amdgcn_mfma_f32_16x16x32_bf16(ah, bh[ni], acc[mi][ni], 0, 0, 0);
                acc[mi][ni] = __builtin_amdgcn_mfma_f32_16x16x32_bf16(ah, bl[ni], acc[mi][ni], 0, 0, 0);
                acc[mi][ni] = __builtin_amdgcn_mfma_f32_16x16x32_bf16(al, bh[ni], acc[mi][ni], 0, 0, 0);
            }
        }

        // ---- all waves done reading this slot -> safe to refill it ----
        asm volatile("" ::: "memory");
        __builtin_amdgcn_s_barrier();
        asm volatile("" ::: "memory");
        if (ra + 2 < NRA) issue_slot(ra + 2, slot);
    }

    // ---- epilogue: relu + norms + argmax + select, two 32-row passes through LDS ----
    // D layout: row = 16*mi + 4*(lane>>4) + j, col = 64*wave + 16*ni + (lane&15)   [m89-verified]
    float* smem = (float*)lds_raw;   // [32][264]
    const int colb = wave * 64 + (lane & 15);
    const int rsub = (lane >> 4) * 4;
#pragma unroll
    for (int ph = 0; ph < 2; ++ph) {
        __syncthreads();
#pragma unroll
        for (int mh = 0; mh < 2; ++mh) {
            int mi = ph * 2 + mh;
#pragma unroll
            for (int ni = 0; ni < 4; ++ni)
#pragma unroll
                for (int j = 0; j < 4; ++j)
                    smem[(mh * 16 + rsub + j) * 264 + colb + ni * 16] =
                        fmaxf(acc[mi][ni][j], 0.0f);
        }
        __syncthreads();
        int bb = tid >> 3;          // 0..31
        int c  = tid & 7;
        float n2 = 0.0f;
#pragma unroll
        for (int t = 0; t < 8; ++t) {
            float4 v = *(const float4*)&smem[bb * 264 + c * 32 + t * 4];
            n2 = fmaf(v.x, v.x, n2); n2 = fmaf(v.y, v.y, n2);
            n2 = fmaf(v.z, v.z, n2); n2 = fmaf(v.w, v.w, n2);
        }
        int bc = c;
#pragma unroll
        for (int m = 1; m < 8; m <<= 1) {   // argmax, tie -> lowest c (numpy first-max)
            float on2 = __shfl_xor(n2, m, 64);
            int obc = __shfl_xor(bc, m, 64);
            if (on2 > n2 || (on2 == n2 && obc < bc)) { n2 = on2; bc = obc; }
        }
        int b = b0 + ph * 32 + bb;
        if (b < B_TOT) {
            float4 v = *(const float4*)&smem[bb * 264 + bc * 32 + (tid & 7) * 4];
            *(float4*)&out[(size_t)b * 32 + (tid & 7) * 4] = v;
        }
    }
}

extern "C" void kernel_launch(void* const* d_in, const int* in_sizes, int n_in,
                              void* d_out, int out_size, void* d_ws, size_t ws_size,
                              hipStream_t stream) {
    const float* sig  = (const float*)d_in[0];   // (B,R,A,3,I)
    const float* bary = (const float*)d_in[1];   // (B,R,A,3)
    const float* kern = (const float*)d_in[2];   // (R,A,K,O,I)
    float* out = (float*)d_out;                  // (B,O)

    build_w_kernel<<<(NRA * 256 * 32) / 256, 256, 0, stream>>>(kern);
    conv_geo_kernel<<<(B_TOT + 63) / 64, 256, 0, stream>>>(sig, bary, out);
}